// Round 4
// baseline (160.827 us; speedup 1.0000x reference)
//
#include <hip/hip_runtime.h>
#include <math.h>

#define CTR_CNT2 0   // |A2|
#define CTR_CNT1 1   // |A1|
#define CTR_E2   2   // #edges into node 0
#define CTR_EB   3   // #edges into A2
#define CTR_EC   4   // #edges into A1

// ---------------- wave helpers (wave64) ----------------
__device__ inline float wave_sum(float v){
  #pragma unroll
  for (int off = 1; off < 64; off <<= 1) v += __shfl_xor(v, off, 64);
  return v;
}

// ---------------- init ----------------
__global__ void k_init(int* __restrict__ flag1, int* __restrict__ flag2,
                       int* __restrict__ list2, int* __restrict__ ctr, int N){
  int i = blockIdx.x * 256 + threadIdx.x;
  if (i < N){
    flag1[i] = 0;
    flag2[i] = (i == 0) ? 1 : 0;   // node 0 = A2 index 0
  }
  if (i < 8) ctr[i] = (i == CTR_CNT2) ? 1 : 0;
  if (i == 0) list2[0] = 0;
}

// ---------------- pass A: edges into node 0; discover A2 ----------------
__global__ void k_passA(const int* __restrict__ ei, int E,
                        int* __restrict__ flag2, int* __restrict__ list2,
                        int* __restrict__ E2src, int* __restrict__ ctr){
  int stride = gridDim.x * 256;
  for (int e = blockIdx.x * 256 + threadIdx.x; e < E; e += stride){
    if (ei[E + e] != 0) continue;
    int s = ei[e];
    E2src[atomicAdd(&ctr[CTR_E2], 1)] = s;
    if (atomicCAS(&flag2[s], 0, -1) == 0){
      int idx = atomicAdd(&ctr[CTR_CNT2], 1);
      list2[idx] = s;
      flag2[s] = idx + 1;
    }
  }
}

// ---------------- seed A1 with A2 (a1idx of an A2 node == its a2idx) ----------------
__global__ void k_seed(const int* __restrict__ list2, int* __restrict__ list1,
                       int* __restrict__ flag1, int* __restrict__ ctr){
  int cnt2 = ctr[CTR_CNT2];
  for (int i = threadIdx.x; i < cnt2; i += 256){
    int v = list2[i];
    list1[i] = v;
    flag1[v] = i + 1;
  }
  if (threadIdx.x == 0) ctr[CTR_CNT1] = cnt2;
}

// ---------------- pass B: compact edges into A2; discover A1 ----------------
__global__ void k_passB(const int* __restrict__ ei, int E,
                        const int* __restrict__ flag2,
                        int* __restrict__ flag1, int* __restrict__ list1,
                        int* __restrict__ EBsrc, int* __restrict__ EBdst,
                        int* __restrict__ ctr){
  int stride = gridDim.x * 256;
  for (int e = blockIdx.x * 256 + threadIdx.x; e < E; e += stride){
    int f = flag2[ei[E + e]];
    if (f <= 0) continue;
    int s = ei[e];
    int p = atomicAdd(&ctr[CTR_EB], 1);
    EBsrc[p] = s; EBdst[p] = f - 1;
    if (atomicCAS(&flag1[s], 0, -1) == 0){
      int idx = atomicAdd(&ctr[CTR_CNT1], 1);
      list1[idx] = s;
      flag1[s] = idx + 1;
    }
  }
}

// ---------------- pass C (blocks>=1) + regroup B-edges (block 0) ----------------
__global__ __launch_bounds__(256) void k_passC_regB(const int* __restrict__ ei, int E,
    const int* __restrict__ flag1,
    int* __restrict__ ECsrc, int* __restrict__ ECdst, int* __restrict__ ctr,
    const int* __restrict__ EBsrc, const int* __restrict__ EBdst,
    int* __restrict__ rowptr1, int* __restrict__ srcs1s){
  if (blockIdx.x == 0){
    // regroup ~700 A2-edges into mini-CSR by a2 idx; store src as a1 idx
    __shared__ int cnts[1024];
    __shared__ int cur[1024];
    int tid = threadIdx.x;
    int cnt2 = ctr[CTR_CNT2], nB = ctr[CTR_EB];
    for (int i = tid; i < cnt2; i += 256) cnts[i] = 0;
    __syncthreads();
    for (int j = tid; j < nB; j += 256) atomicAdd(&cnts[EBdst[j]], 1);
    __syncthreads();
    if (tid == 0){
      int run = 0;
      for (int k = 0; k < cnt2; ++k){ rowptr1[k] = run; cur[k] = run; run += cnts[k]; }
      rowptr1[cnt2] = run;
    }
    __syncthreads();
    for (int j = tid; j < nB; j += 256){
      int pos = atomicAdd(&cur[EBdst[j]], 1);
      srcs1s[pos] = flag1[EBsrc[j]] - 1;   // a1 index
    }
  } else {
    int stride = (gridDim.x - 1) * 256;
    for (int e = (blockIdx.x - 1) * 256 + threadIdx.x; e < E; e += stride){
      int f = flag1[ei[E + e]];
      if (f <= 0) continue;
      int p = atomicAdd(&ctr[CTR_EC], 1);
      ECsrc[p] = ei[e]; ECdst[p] = f - 1;
    }
  }
}

// ---------------- regroup C-edges into mini-CSR by a1 idx ----------------
__global__ __launch_bounds__(256) void k_regC(const int* __restrict__ ECsrc,
    const int* __restrict__ ECdst,
    int* __restrict__ rowptr0, int* __restrict__ srcs0s,
    const int* __restrict__ ctr){
  __shared__ int cnts[8192];
  __shared__ int cur[8192];
  int tid = threadIdx.x;
  int cnt1 = ctr[CTR_CNT1], nC = ctr[CTR_EC];
  if (cnt1 > 8192) cnt1 = 8192;   // safety clamp (never hit for this input)
  for (int i = tid; i < cnt1; i += 256) cnts[i] = 0;
  __syncthreads();
  for (int j = tid; j < nC; j += 256){
    int d = ECdst[j];
    if (d < 8192) atomicAdd(&cnts[d], 1);
  }
  __syncthreads();
  if (tid == 0){
    int run = 0;
    for (int k = 0; k < cnt1; ++k){ rowptr0[k] = run; cur[k] = run; run += cnts[k]; }
    rowptr0[cnt1] = run;
  }
  __syncthreads();
  for (int j = tid; j < nC; j += 256){
    int d = ECdst[j];
    if (d < 8192){
      int pos = atomicAdd(&cur[d], 1);
      srcs0s[pos] = ECsrc[j];   // node id (layer 0 reads x[s] directly)
    }
  }
}

// ---------------- L0: flash agg + LN + ELU + fused layer-1 xl/xr GEMVs ----------------
__global__ __launch_bounds__(256) void k_L0(const float* __restrict__ x,
    const float* __restrict__ Wl0, const float* __restrict__ bl0,
    const float* __restrict__ Wr0, const float* __restrict__ br0,
    const float* __restrict__ att0, const float* __restrict__ bias0,
    const float* __restrict__ g0, const float* __restrict__ be0,
    const float* __restrict__ Wl1, const float* __restrict__ bl1,
    const float* __restrict__ Wr1, const float* __restrict__ br1,
    const int* __restrict__ list1, const int* __restrict__ rowptr0,
    const int* __restrict__ srcs0s, const int* __restrict__ flag2,
    const int* __restrict__ ctr,
    float* __restrict__ xl1, float* __restrict__ xr1buf){
  int tid = threadIdx.x, h = tid >> 6, lane = tid & 63;
  float wl = Wl0[tid], blv = bl0[tid], wr = Wr0[tid], brv = br0[tid];
  float at = att0[tid], bs = bias0[tid], gv = g0[tid], bev = be0[tid];
  float bl1v = bl1[tid], br1v = br1[tid];
  __shared__ float red[4];
  __shared__ float hs[256];
  int cnt1 = ctr[CTR_CNT1];
  for (int i = blockIdx.x; i < cnt1; i += gridDim.x){
    int v = list1[i];
    float xr = fmaf(x[v], wr, brv);
    int r0 = rowptr0[i], r1 = rowptr0[i + 1];
    float m = -INFINITY, ssum = 0.f, acc = 0.f;
    for (int e = r0; e <= r1; ++e){          // slot r1 = synthetic self-loop
      int s = (e < r1) ? srcs0s[e] : v;
      float xls = fmaf(x[s], wl, blv);
      float a = xls + xr;
      a = (a > 0.f) ? a : 0.2f * a;
      float lg = wave_sum(at * a);
      float mn = fmaxf(m, lg);
      float sc = expf(m - mn), p = expf(lg - mn);
      ssum = fmaf(ssum, sc, p);
      acc  = fmaf(acc,  sc, p * xls);
      m = mn;
    }
    float o = acc / (ssum + 1e-16f) + bs;
    float s1 = wave_sum(o);
    if (lane == 0) red[h] = s1;
    __syncthreads();
    float mu = (red[0] + red[1] + red[2] + red[3]) * (1.f / 256.f);
    float dv = o - mu;
    __syncthreads();
    float s2 = wave_sum(dv * dv);
    if (lane == 0) red[h] = s2;
    __syncthreads();
    float var = (red[0] + red[1] + red[2] + red[3]) * (1.f / 256.f);
    float y = dv * rsqrtf(var + 1e-5f) * gv + bev;
    float h0v = (y > 0.f) ? y : expm1f(y);
    hs[tid] = h0v;
    __syncthreads();
    // fused layer-1 projections from LDS h0
    float xlv = bl1v;
    #pragma unroll 8
    for (int k = 0; k < 256; ++k) xlv = fmaf(hs[k], Wl1[(size_t)k * 256 + tid], xlv);
    xl1[(size_t)i * 256 + tid] = xlv;
    int f2 = flag2[v];
    if (f2 > 0){
      float xrv = br1v;
      #pragma unroll 8
      for (int k = 0; k < 256; ++k) xrv = fmaf(hs[k], Wr1[(size_t)k * 256 + tid], xrv);
      xr1buf[(size_t)(f2 - 1) * 256 + tid] = xrv;
    }
    __syncthreads();
  }
}

// ---------------- L1: flash agg + LN + ELU + fused layer-2 xl/xr GEMVs ----------------
__global__ __launch_bounds__(256) void k_L1(const float* __restrict__ xl1,
    const float* __restrict__ xr1buf,
    const float* __restrict__ att1, const float* __restrict__ bias1,
    const float* __restrict__ g1, const float* __restrict__ be1,
    const float* __restrict__ Wl2, const float* __restrict__ bl2,
    const float* __restrict__ Wr2, const float* __restrict__ br2,
    const int* __restrict__ rowptr1, const int* __restrict__ srcs1s,
    const int* __restrict__ ctr,
    float* __restrict__ xl2, float* __restrict__ xr2){
  int tid = threadIdx.x, h = tid >> 6, lane = tid & 63;
  float at = att1[tid];
  __shared__ float red[4];
  __shared__ float hs[256];
  int cnt2 = ctr[CTR_CNT2];
  for (int i = blockIdx.x; i < cnt2; i += gridDim.x){
    float xr = xr1buf[(size_t)i * 256 + tid];
    int r0 = rowptr1[i], r1 = rowptr1[i + 1];
    float m = -INFINITY, ssum = 0.f, acc = 0.f;
    for (int e = r0; e <= r1; ++e){
      int si = (e < r1) ? srcs1s[e] : i;   // a1 idx; self-loop: a1idx == a2idx == i
      float xls = xl1[(size_t)si * 256 + tid];
      float a = xls + xr;
      a = (a > 0.f) ? a : 0.2f * a;
      float lg = wave_sum(at * a);
      float mn = fmaxf(m, lg);
      float sc = expf(m - mn), p = expf(lg - mn);
      ssum = fmaf(ssum, sc, p);
      acc  = fmaf(acc,  sc, p * xls);
      m = mn;
    }
    float o = acc / (ssum + 1e-16f) + bias1[tid];
    float s1 = wave_sum(o);
    if (lane == 0) red[h] = s1;
    __syncthreads();
    float mu = (red[0] + red[1] + red[2] + red[3]) * (1.f / 256.f);
    float dv = o - mu;
    __syncthreads();
    float s2 = wave_sum(dv * dv);
    if (lane == 0) red[h] = s2;
    __syncthreads();
    float var = (red[0] + red[1] + red[2] + red[3]) * (1.f / 256.f);
    float y = dv * rsqrtf(var + 1e-5f) * g1[tid] + be1[tid];
    float h1v = (y > 0.f) ? y : expm1f(y);
    hs[tid] = h1v;
    __syncthreads();
    if (tid < 64){
      float a2 = bl2[tid];
      #pragma unroll 8
      for (int k = 0; k < 256; ++k) a2 = fmaf(hs[k], Wl2[(size_t)k * 64 + tid], a2);
      xl2[(size_t)i * 64 + tid] = a2;
      if (i == 0){
        float b2 = br2[tid];
        #pragma unroll 8
        for (int k = 0; k < 256; ++k) b2 = fmaf(hs[k], Wr2[(size_t)k * 64 + tid], b2);
        xr2[tid] = b2;
      }
    }
    __syncthreads();
  }
}

// ---------------- final: layer-2 flash agg for node 0 + LN + ELU + head MLP ----------------
__global__ __launch_bounds__(64) void k_final(const float* __restrict__ xl2,
    const float* __restrict__ xr2,
    const float* __restrict__ att2, const float* __restrict__ bias2,
    const float* __restrict__ g2, const float* __restrict__ be2,
    const float* __restrict__ rw1, const float* __restrict__ rb1,
    const float* __restrict__ rw2, const float* __restrict__ rb2,
    const int* __restrict__ E2src, const int* __restrict__ flag2,
    const int* __restrict__ ctr, float* __restrict__ out){
  int lane = threadIdx.x;
  float xr = xr2[lane], at = att2[lane];
  int ne = ctr[CTR_E2];
  float m = -INFINITY, ssum = 0.f, acc = 0.f;
  for (int e = 0; e <= ne; ++e){
    int idx = (e < ne) ? (flag2[E2src[e]] - 1) : 0;
    float xls = xl2[(size_t)idx * 64 + lane];
    float a = xls + xr;
    a = (a > 0.f) ? a : 0.2f * a;
    float lg = wave_sum(at * a);
    float mn = fmaxf(m, lg);
    float sc = expf(m - mn), p = expf(lg - mn);
    ssum = fmaf(ssum, sc, p);
    acc  = fmaf(acc,  sc, p * xls);
    m = mn;
  }
  float o = acc / (ssum + 1e-16f) + bias2[lane];
  float mu = wave_sum(o) * (1.f / 64.f);
  float dv = o - mu;
  float var = wave_sum(dv * dv) * (1.f / 64.f);
  float y = dv * rsqrtf(var + 1e-5f) * g2[lane] + be2[lane];
  float hv_v = (y > 0.f) ? y : expm1f(y);
  __shared__ float hv[64];
  hv[lane] = hv_v;
  __syncthreads();
  float contrib = 0.f;
  if (lane < 32){
    float a = rb1[lane];
    #pragma unroll 8
    for (int c = 0; c < 64; ++c) a = fmaf(hv[c], rw1[c * 32 + lane], a);
    float z = 0.5f * a * (1.f + erff(a * 0.70710678118654752f));
    contrib = z * rw2[lane];
  }
  float sfin = wave_sum(contrib);
  if (lane == 0) out[0] = sfin + rb2[0];
}

// ---------------- launch ----------------
extern "C" void kernel_launch(void* const* d_in, const int* in_sizes, int n_in,
                              void* d_out, int out_size, void* d_ws, size_t ws_size,
                              hipStream_t stream){
  const float* x    = (const float*)d_in[0];
  const int*   ei   = (const int*)  d_in[1];
  const float* Wl0  = (const float*)d_in[2];
  const float* bl0  = (const float*)d_in[3];
  const float* Wr0  = (const float*)d_in[4];
  const float* br0  = (const float*)d_in[5];
  const float* att0 = (const float*)d_in[6];
  const float* bias0= (const float*)d_in[7];
  const float* Wl1  = (const float*)d_in[8];
  const float* bl1  = (const float*)d_in[9];
  const float* Wr1  = (const float*)d_in[10];
  const float* br1  = (const float*)d_in[11];
  const float* att1 = (const float*)d_in[12];
  const float* bias1= (const float*)d_in[13];
  const float* Wl2  = (const float*)d_in[14];
  const float* bl2  = (const float*)d_in[15];
  const float* Wr2  = (const float*)d_in[16];
  const float* br2  = (const float*)d_in[17];
  const float* att2 = (const float*)d_in[18];
  const float* bias2= (const float*)d_in[19];
  const float* g0   = (const float*)d_in[20];
  const float* be0  = (const float*)d_in[21];
  const float* g1   = (const float*)d_in[22];
  const float* be1  = (const float*)d_in[23];
  const float* g2   = (const float*)d_in[24];
  const float* be2  = (const float*)d_in[25];
  const float* rw1  = (const float*)d_in[26];
  const float* rb1  = (const float*)d_in[27];
  const float* rw2  = (const float*)d_in[28];
  const float* rb2  = (const float*)d_in[29];

  const int N = in_sizes[0];        // 50000
  const int E = in_sizes[1] / 2;    // 800000

  char* ws = (char*)d_ws;
  size_t off = 0;
  auto alloc = [&](size_t bytes) -> char* {
    char* p = ws + off;
    off += (bytes + 255) & ~(size_t)255;
    return p;
  };
  int*   ctr     = (int*)  alloc(64);
  int*   flag1   = (int*)  alloc((size_t)N * 4);
  int*   flag2   = (int*)  alloc((size_t)N * 4);
  int*   list1   = (int*)  alloc((size_t)N * 4);
  int*   list2   = (int*)  alloc((size_t)N * 4);
  int*   E2src   = (int*)  alloc((size_t)E * 4);
  int*   EBsrc   = (int*)  alloc((size_t)E * 4);
  int*   EBdst   = (int*)  alloc((size_t)E * 4);
  int*   ECsrc   = (int*)  alloc((size_t)E * 4);
  int*   ECdst   = (int*)  alloc((size_t)E * 4);
  int*   rowptr0 = (int*)  alloc((size_t)(N + 1) * 4);
  int*   rowptr1 = (int*)  alloc((size_t)(N + 1) * 4);
  int*   srcs0s  = (int*)  alloc((size_t)E * 4);
  int*   srcs1s  = (int*)  alloc((size_t)E * 4);
  float* xr2     = (float*)alloc(64 * 4);
  float* xl2     = (float*)alloc((size_t)N * 64 * 4);
  float* xl1     = (float*)alloc((size_t)N * 256 * 4);
  float* xr1buf  = (float*)alloc((size_t)N * 256 * 4);
  (void)ws_size; (void)n_in; (void)out_size;

  int nb = (N + 255) / 256;

  k_init      <<<nb, 256, 0, stream>>>(flag1, flag2, list2, ctr, N);
  k_passA     <<<1024, 256, 0, stream>>>(ei, E, flag2, list2, E2src, ctr);
  k_seed      <<<1, 256, 0, stream>>>(list2, list1, flag1, ctr);
  k_passB     <<<1024, 256, 0, stream>>>(ei, E, flag2, flag1, list1, EBsrc, EBdst, ctr);
  k_passC_regB<<<1024, 256, 0, stream>>>(ei, E, flag1, ECsrc, ECdst, ctr,
                                         EBsrc, EBdst, rowptr1, srcs1s);
  k_regC      <<<1, 256, 0, stream>>>(ECsrc, ECdst, rowptr0, srcs0s, ctr);
  k_L0        <<<512, 256, 0, stream>>>(x, Wl0, bl0, Wr0, br0, att0, bias0, g0, be0,
                                        Wl1, bl1, Wr1, br1,
                                        list1, rowptr0, srcs0s, flag2, ctr, xl1, xr1buf);
  k_L1        <<<64, 256, 0, stream>>>(xl1, xr1buf, att1, bias1, g1, be1,
                                       Wl2, bl2, Wr2, br2,
                                       rowptr1, srcs1s, ctr, xl2, xr2);
  k_final     <<<1, 64, 0, stream>>>(xl2, xr2, att2, bias2, g2, be2,
                                     rw1, rb1, rw2, rb2, E2src, flag2, ctr, (float*)d_out);
}

// Round 5
// 126.222 us; speedup vs baseline: 1.2742x; 1.2742x over previous
//
#include <hip/hip_runtime.h>
#include <math.h>

#define CTR_CNT2 0   // |A2|
#define CTR_CNT1 1   // |A1|
#define CTR_E2   2   // #edges into node 0
#define CTR_EB   3   // #edges into A2
#define CTR_EC   4   // #edges into A1

// ---------------- wave helpers (wave64) ----------------
__device__ inline float wave_sum(float v){
  #pragma unroll
  for (int off = 1; off < 64; off <<= 1) v += __shfl_xor(v, off, 64);
  return v;
}

// ---------------- init ----------------
__global__ void k_init(int* __restrict__ flag1, int* __restrict__ flag2,
                       int* __restrict__ list2, int* __restrict__ ctr, int N){
  int i = blockIdx.x * 256 + threadIdx.x;
  if (i < N){
    flag1[i] = 0;
    flag2[i] = (i == 0) ? 1 : 0;   // node 0 = A2 index 0
  }
  if (i < 8) ctr[i] = (i == CTR_CNT2) ? 1 : 0;
  if (i == 0) list2[0] = 0;
}

// ---------------- pass A: edges into node 0; discover A2 ----------------
// two-phase block compaction: 1 global atomic per block
__global__ __launch_bounds__(256) void k_passA(const int* __restrict__ ei, int E,
                        int* __restrict__ flag2, int* __restrict__ list2,
                        int* __restrict__ E2src, int* __restrict__ ctr){
  __shared__ int bcnt, lcur, gbase;
  int tid = threadIdx.x;
  int chunk = (E + gridDim.x - 1) / gridDim.x;
  int lo = blockIdx.x * chunk;
  int hi = min(E, lo + chunk);
  if (tid == 0){ bcnt = 0; lcur = 0; }
  __syncthreads();
  int cnt = 0;
  for (int e = lo + tid; e < hi; e += 256) if (ei[E + e] == 0) cnt++;
  if (cnt) atomicAdd(&bcnt, cnt);
  __syncthreads();
  if (tid == 0) gbase = bcnt ? atomicAdd(&ctr[CTR_E2], bcnt) : 0;
  __syncthreads();
  for (int e = lo + tid; e < hi; e += 256){
    if (ei[E + e] != 0) continue;
    int s = ei[e];
    E2src[gbase + atomicAdd(&lcur, 1)] = s;
    if (atomicCAS(&flag2[s], 0, -1) == 0){
      int idx = atomicAdd(&ctr[CTR_CNT2], 1);
      list2[idx] = s;
      flag2[s] = idx + 1;
    }
  }
}

// ---------------- seed A1 with A2 (a1idx of an A2 node == its a2idx) ----------------
__global__ void k_seed(const int* __restrict__ list2, int* __restrict__ list1,
                       int* __restrict__ flag1, int* __restrict__ ctr){
  int cnt2 = ctr[CTR_CNT2];
  for (int i = threadIdx.x; i < cnt2; i += 256){
    int v = list2[i];
    list1[i] = v;
    flag1[v] = i + 1;
  }
  if (threadIdx.x == 0) ctr[CTR_CNT1] = cnt2;
}

// ---------------- pass B: compact edges into A2; discover A1 ----------------
__global__ __launch_bounds__(256) void k_passB(const int* __restrict__ ei, int E,
                        const int* __restrict__ flag2,
                        int* __restrict__ flag1, int* __restrict__ list1,
                        int* __restrict__ EBsrc, int* __restrict__ EBdst,
                        int* __restrict__ ctr){
  __shared__ int bcnt, lcur, gbase;
  int tid = threadIdx.x;
  int chunk = (E + gridDim.x - 1) / gridDim.x;
  int lo = blockIdx.x * chunk;
  int hi = min(E, lo + chunk);
  if (tid == 0){ bcnt = 0; lcur = 0; }
  __syncthreads();
  int cnt = 0;
  for (int e = lo + tid; e < hi; e += 256) if (flag2[ei[E + e]] > 0) cnt++;
  if (cnt) atomicAdd(&bcnt, cnt);
  __syncthreads();
  if (tid == 0) gbase = bcnt ? atomicAdd(&ctr[CTR_EB], bcnt) : 0;
  __syncthreads();
  for (int e = lo + tid; e < hi; e += 256){
    int f = flag2[ei[E + e]];
    if (f <= 0) continue;
    int s = ei[e];
    int p = gbase + atomicAdd(&lcur, 1);
    EBsrc[p] = s; EBdst[p] = f - 1;
    if (atomicCAS(&flag1[s], 0, -1) == 0){
      int idx = atomicAdd(&ctr[CTR_CNT1], 1);
      list1[idx] = s;
      flag1[s] = idx + 1;
    }
  }
}

// ---------------- pass C (blocks>=1, chunked) + regroup B-edges (block 0) ----------------
__global__ __launch_bounds__(256) void k_passC_regB(const int* __restrict__ ei, int E,
    const int* __restrict__ flag1,
    int* __restrict__ ECsrc, int* __restrict__ ECdst, int* __restrict__ ctr,
    const int* __restrict__ EBsrc, const int* __restrict__ EBdst,
    int* __restrict__ rowptr1, int* __restrict__ srcs1s){
  int tid = threadIdx.x;
  if (blockIdx.x == 0){
    // regroup ~700 A2-edges into mini-CSR by a2 idx; store src as a1 idx
    __shared__ int cnts[1024];
    __shared__ int cur[1024];
    int cnt2 = ctr[CTR_CNT2], nB = ctr[CTR_EB];
    for (int i = tid; i < cnt2; i += 256) cnts[i] = 0;
    __syncthreads();
    for (int j = tid; j < nB; j += 256) atomicAdd(&cnts[EBdst[j]], 1);
    __syncthreads();
    if (tid == 0){
      int run = 0;
      for (int k = 0; k < cnt2; ++k){ rowptr1[k] = run; cur[k] = run; run += cnts[k]; }
      rowptr1[cnt2] = run;
    }
    __syncthreads();
    for (int j = tid; j < nB; j += 256){
      int pos = atomicAdd(&cur[EBdst[j]], 1);
      srcs1s[pos] = flag1[EBsrc[j]] - 1;   // a1 index
    }
  } else {
    __shared__ int bcnt, lcur, gbase;
    int nblk = gridDim.x - 1;
    int chunk = (E + nblk - 1) / nblk;
    int lo = (blockIdx.x - 1) * chunk;
    int hi = min(E, lo + chunk);
    if (tid == 0){ bcnt = 0; lcur = 0; }
    __syncthreads();
    int cnt = 0;
    for (int e = lo + tid; e < hi; e += 256) if (flag1[ei[E + e]] > 0) cnt++;
    if (cnt) atomicAdd(&bcnt, cnt);
    __syncthreads();
    if (tid == 0) gbase = bcnt ? atomicAdd(&ctr[CTR_EC], bcnt) : 0;
    __syncthreads();
    for (int e = lo + tid; e < hi; e += 256){
      int f = flag1[ei[E + e]];
      if (f <= 0) continue;
      int p = gbase + atomicAdd(&lcur, 1);
      ECsrc[p] = ei[e]; ECdst[p] = f - 1;
    }
  }
}

// ---------------- regroup C-edges into mini-CSR by a1 idx ----------------
__global__ __launch_bounds__(256) void k_regC(const int* __restrict__ ECsrc,
    const int* __restrict__ ECdst,
    int* __restrict__ rowptr0, int* __restrict__ srcs0s,
    const int* __restrict__ ctr){
  __shared__ int cnts[8192];
  __shared__ int cur[8192];
  int tid = threadIdx.x;
  int cnt1 = ctr[CTR_CNT1], nC = ctr[CTR_EC];
  if (cnt1 > 8192) cnt1 = 8192;   // safety clamp (never hit for this input)
  for (int i = tid; i < cnt1; i += 256) cnts[i] = 0;
  __syncthreads();
  for (int j = tid; j < nC; j += 256){
    int d = ECdst[j];
    if (d < 8192) atomicAdd(&cnts[d], 1);
  }
  __syncthreads();
  if (tid == 0){
    int run = 0;
    for (int k = 0; k < cnt1; ++k){ rowptr0[k] = run; cur[k] = run; run += cnts[k]; }
    rowptr0[cnt1] = run;
  }
  __syncthreads();
  for (int j = tid; j < nC; j += 256){
    int d = ECdst[j];
    if (d < 8192){
      int pos = atomicAdd(&cur[d], 1);
      srcs0s[pos] = ECsrc[j];   // node id (layer 0 reads x[s] directly)
    }
  }
}

// ---------------- L0: flash agg + LN + ELU + fused layer-1 xl/xr GEMVs ----------------
__global__ __launch_bounds__(256) void k_L0(const float* __restrict__ x,
    const float* __restrict__ Wl0, const float* __restrict__ bl0,
    const float* __restrict__ Wr0, const float* __restrict__ br0,
    const float* __restrict__ att0, const float* __restrict__ bias0,
    const float* __restrict__ g0, const float* __restrict__ be0,
    const float* __restrict__ Wl1, const float* __restrict__ bl1,
    const float* __restrict__ Wr1, const float* __restrict__ br1,
    const int* __restrict__ list1, const int* __restrict__ rowptr0,
    const int* __restrict__ srcs0s, const int* __restrict__ flag2,
    const int* __restrict__ ctr,
    float* __restrict__ xl1, float* __restrict__ xr1buf){
  int tid = threadIdx.x, h = tid >> 6, lane = tid & 63;
  float wl = Wl0[tid], blv = bl0[tid], wr = Wr0[tid], brv = br0[tid];
  float at = att0[tid], bs = bias0[tid], gv = g0[tid], bev = be0[tid];
  float bl1v = bl1[tid], br1v = br1[tid];
  __shared__ float red[4];
  __shared__ float hs[256];
  int cnt1 = ctr[CTR_CNT1];
  for (int i = blockIdx.x; i < cnt1; i += gridDim.x){
    int v = list1[i];
    float xr = fmaf(x[v], wr, brv);
    int r0 = rowptr0[i], r1 = rowptr0[i + 1];
    float m = -INFINITY, ssum = 0.f, acc = 0.f;
    for (int e = r0; e <= r1; ++e){          // slot r1 = synthetic self-loop
      int s = (e < r1) ? srcs0s[e] : v;
      float xls = fmaf(x[s], wl, blv);
      float a = xls + xr;
      a = (a > 0.f) ? a : 0.2f * a;
      float lg = wave_sum(at * a);
      float mn = fmaxf(m, lg);
      float sc = expf(m - mn), p = expf(lg - mn);
      ssum = fmaf(ssum, sc, p);
      acc  = fmaf(acc,  sc, p * xls);
      m = mn;
    }
    float o = acc / (ssum + 1e-16f) + bs;
    float s1 = wave_sum(o);
    if (lane == 0) red[h] = s1;
    __syncthreads();
    float mu = (red[0] + red[1] + red[2] + red[3]) * (1.f / 256.f);
    float dv = o - mu;
    __syncthreads();
    float s2 = wave_sum(dv * dv);
    if (lane == 0) red[h] = s2;
    __syncthreads();
    float var = (red[0] + red[1] + red[2] + red[3]) * (1.f / 256.f);
    float y = dv * rsqrtf(var + 1e-5f) * gv + bev;
    float h0v = (y > 0.f) ? y : expm1f(y);
    hs[tid] = h0v;
    __syncthreads();
    // fused layer-1 projections from LDS h0
    float xlv = bl1v;
    #pragma unroll 8
    for (int k = 0; k < 256; ++k) xlv = fmaf(hs[k], Wl1[(size_t)k * 256 + tid], xlv);
    xl1[(size_t)i * 256 + tid] = xlv;
    int f2 = flag2[v];
    if (f2 > 0){
      float xrv = br1v;
      #pragma unroll 8
      for (int k = 0; k < 256; ++k) xrv = fmaf(hs[k], Wr1[(size_t)k * 256 + tid], xrv);
      xr1buf[(size_t)(f2 - 1) * 256 + tid] = xrv;
    }
    __syncthreads();
  }
}

// ---------------- L1: flash agg + LN + ELU + fused layer-2 xl/xr GEMVs ----------------
__global__ __launch_bounds__(256) void k_L1(const float* __restrict__ xl1,
    const float* __restrict__ xr1buf,
    const float* __restrict__ att1, const float* __restrict__ bias1,
    const float* __restrict__ g1, const float* __restrict__ be1,
    const float* __restrict__ Wl2, const float* __restrict__ bl2,
    const float* __restrict__ Wr2, const float* __restrict__ br2,
    const int* __restrict__ rowptr1, const int* __restrict__ srcs1s,
    const int* __restrict__ ctr,
    float* __restrict__ xl2, float* __restrict__ xr2){
  int tid = threadIdx.x, h = tid >> 6, lane = tid & 63;
  float at = att1[tid];
  __shared__ float red[4];
  __shared__ float hs[256];
  int cnt2 = ctr[CTR_CNT2];
  for (int i = blockIdx.x; i < cnt2; i += gridDim.x){
    float xr = xr1buf[(size_t)i * 256 + tid];
    int r0 = rowptr1[i], r1 = rowptr1[i + 1];
    float m = -INFINITY, ssum = 0.f, acc = 0.f;
    for (int e = r0; e <= r1; ++e){
      int si = (e < r1) ? srcs1s[e] : i;   // a1 idx; self-loop: a1idx == a2idx == i
      float xls = xl1[(size_t)si * 256 + tid];
      float a = xls + xr;
      a = (a > 0.f) ? a : 0.2f * a;
      float lg = wave_sum(at * a);
      float mn = fmaxf(m, lg);
      float sc = expf(m - mn), p = expf(lg - mn);
      ssum = fmaf(ssum, sc, p);
      acc  = fmaf(acc,  sc, p * xls);
      m = mn;
    }
    float o = acc / (ssum + 1e-16f) + bias1[tid];
    float s1 = wave_sum(o);
    if (lane == 0) red[h] = s1;
    __syncthreads();
    float mu = (red[0] + red[1] + red[2] + red[3]) * (1.f / 256.f);
    float dv = o - mu;
    __syncthreads();
    float s2 = wave_sum(dv * dv);
    if (lane == 0) red[h] = s2;
    __syncthreads();
    float var = (red[0] + red[1] + red[2] + red[3]) * (1.f / 256.f);
    float y = dv * rsqrtf(var + 1e-5f) * g1[tid] + be1[tid];
    float h1v = (y > 0.f) ? y : expm1f(y);
    hs[tid] = h1v;
    __syncthreads();
    if (tid < 64){
      float a2 = bl2[tid];
      #pragma unroll 8
      for (int k = 0; k < 256; ++k) a2 = fmaf(hs[k], Wl2[(size_t)k * 64 + tid], a2);
      xl2[(size_t)i * 64 + tid] = a2;
      if (i == 0){
        float b2 = br2[tid];
        #pragma unroll 8
        for (int k = 0; k < 256; ++k) b2 = fmaf(hs[k], Wr2[(size_t)k * 64 + tid], b2);
        xr2[tid] = b2;
      }
    }
    __syncthreads();
  }
}

// ---------------- final: layer-2 flash agg for node 0 + LN + ELU + head MLP ----------------
__global__ __launch_bounds__(64) void k_final(const float* __restrict__ xl2,
    const float* __restrict__ xr2,
    const float* __restrict__ att2, const float* __restrict__ bias2,
    const float* __restrict__ g2, const float* __restrict__ be2,
    const float* __restrict__ rw1, const float* __restrict__ rb1,
    const float* __restrict__ rw2, const float* __restrict__ rb2,
    const int* __restrict__ E2src, const int* __restrict__ flag2,
    const int* __restrict__ ctr, float* __restrict__ out){
  int lane = threadIdx.x;
  float xr = xr2[lane], at = att2[lane];
  int ne = ctr[CTR_E2];
  float m = -INFINITY, ssum = 0.f, acc = 0.f;
  for (int e = 0; e <= ne; ++e){
    int idx = (e < ne) ? (flag2[E2src[e]] - 1) : 0;
    float xls = xl2[(size_t)idx * 64 + lane];
    float a = xls + xr;
    a = (a > 0.f) ? a : 0.2f * a;
    float lg = wave_sum(at * a);
    float mn = fmaxf(m, lg);
    float sc = expf(m - mn), p = expf(lg - mn);
    ssum = fmaf(ssum, sc, p);
    acc  = fmaf(acc,  sc, p * xls);
    m = mn;
  }
  float o = acc / (ssum + 1e-16f) + bias2[lane];
  float mu = wave_sum(o) * (1.f / 64.f);
  float dv = o - mu;
  float var = wave_sum(dv * dv) * (1.f / 64.f);
  float y = dv * rsqrtf(var + 1e-5f) * g2[lane] + be2[lane];
  float hv_v = (y > 0.f) ? y : expm1f(y);
  __shared__ float hv[64];
  hv[lane] = hv_v;
  __syncthreads();
  float contrib = 0.f;
  if (lane < 32){
    float a = rb1[lane];
    #pragma unroll 8
    for (int c = 0; c < 64; ++c) a = fmaf(hv[c], rw1[c * 32 + lane], a);
    float z = 0.5f * a * (1.f + erff(a * 0.70710678118654752f));
    contrib = z * rw2[lane];
  }
  float sfin = wave_sum(contrib);
  if (lane == 0) out[0] = sfin + rb2[0];
}

// ---------------- launch ----------------
extern "C" void kernel_launch(void* const* d_in, const int* in_sizes, int n_in,
                              void* d_out, int out_size, void* d_ws, size_t ws_size,
                              hipStream_t stream){
  const float* x    = (const float*)d_in[0];
  const int*   ei   = (const int*)  d_in[1];
  const float* Wl0  = (const float*)d_in[2];
  const float* bl0  = (const float*)d_in[3];
  const float* Wr0  = (const float*)d_in[4];
  const float* br0  = (const float*)d_in[5];
  const float* att0 = (const float*)d_in[6];
  const float* bias0= (const float*)d_in[7];
  const float* Wl1  = (const float*)d_in[8];
  const float* bl1  = (const float*)d_in[9];
  const float* Wr1  = (const float*)d_in[10];
  const float* br1  = (const float*)d_in[11];
  const float* att1 = (const float*)d_in[12];
  const float* bias1= (const float*)d_in[13];
  const float* Wl2  = (const float*)d_in[14];
  const float* bl2  = (const float*)d_in[15];
  const float* Wr2  = (const float*)d_in[16];
  const float* br2  = (const float*)d_in[17];
  const float* att2 = (const float*)d_in[18];
  const float* bias2= (const float*)d_in[19];
  const float* g0   = (const float*)d_in[20];
  const float* be0  = (const float*)d_in[21];
  const float* g1   = (const float*)d_in[22];
  const float* be1  = (const float*)d_in[23];
  const float* g2   = (const float*)d_in[24];
  const float* be2  = (const float*)d_in[25];
  const float* rw1  = (const float*)d_in[26];
  const float* rb1  = (const float*)d_in[27];
  const float* rw2  = (const float*)d_in[28];
  const float* rb2  = (const float*)d_in[29];

  const int N = in_sizes[0];        // 50000
  const int E = in_sizes[1] / 2;    // 800000

  char* ws = (char*)d_ws;
  size_t off = 0;
  auto alloc = [&](size_t bytes) -> char* {
    char* p = ws + off;
    off += (bytes + 255) & ~(size_t)255;
    return p;
  };
  int*   ctr     = (int*)  alloc(64);
  int*   flag1   = (int*)  alloc((size_t)N * 4);
  int*   flag2   = (int*)  alloc((size_t)N * 4);
  int*   list1   = (int*)  alloc((size_t)N * 4);
  int*   list2   = (int*)  alloc((size_t)N * 4);
  int*   E2src   = (int*)  alloc((size_t)E * 4);
  int*   EBsrc   = (int*)  alloc((size_t)E * 4);
  int*   EBdst   = (int*)  alloc((size_t)E * 4);
  int*   ECsrc   = (int*)  alloc((size_t)E * 4);
  int*   ECdst   = (int*)  alloc((size_t)E * 4);
  int*   rowptr0 = (int*)  alloc((size_t)(N + 1) * 4);
  int*   rowptr1 = (int*)  alloc((size_t)(N + 1) * 4);
  int*   srcs0s  = (int*)  alloc((size_t)E * 4);
  int*   srcs1s  = (int*)  alloc((size_t)E * 4);
  float* xr2     = (float*)alloc(64 * 4);
  float* xl2     = (float*)alloc((size_t)N * 64 * 4);
  float* xl1     = (float*)alloc((size_t)N * 256 * 4);
  float* xr1buf  = (float*)alloc((size_t)N * 256 * 4);
  (void)ws_size; (void)n_in; (void)out_size;

  int nb = (N + 255) / 256;

  k_init      <<<nb, 256, 0, stream>>>(flag1, flag2, list2, ctr, N);
  k_passA     <<<256, 256, 0, stream>>>(ei, E, flag2, list2, E2src, ctr);
  k_seed      <<<1, 256, 0, stream>>>(list2, list1, flag1, ctr);
  k_passB     <<<256, 256, 0, stream>>>(ei, E, flag2, flag1, list1, EBsrc, EBdst, ctr);
  k_passC_regB<<<257, 256, 0, stream>>>(ei, E, flag1, ECsrc, ECdst, ctr,
                                        EBsrc, EBdst, rowptr1, srcs1s);
  k_regC      <<<1, 256, 0, stream>>>(ECsrc, ECdst, rowptr0, srcs0s, ctr);
  k_L0        <<<512, 256, 0, stream>>>(x, Wl0, bl0, Wr0, br0, att0, bias0, g0, be0,
                                        Wl1, bl1, Wr1, br1,
                                        list1, rowptr0, srcs0s, flag2, ctr, xl1, xr1buf);
  k_L1        <<<64, 256, 0, stream>>>(xl1, xr1buf, att1, bias1, g1, be1,
                                       Wl2, bl2, Wr2, br2,
                                       rowptr1, srcs1s, ctr, xl2, xr2);
  k_final     <<<1, 64, 0, stream>>>(xl2, xr2, att2, bias2, g2, be2,
                                     rw1, rb1, rw2, rb2, E2src, flag2, ctr, (float*)d_out);
}